// Round 20
// baseline (55.647 us; speedup 1.0000x reference)
//
#include <hip/hip_runtime.h>

#define NBINS   1024
#define TARGETC 192
#define CAPW    256
#define DET     100
#define XCLIP   4.135166556742356f
#define CHUNK   24
#define TILE4   576    // 546 used float4 slots + clamp pad
#define K1GRID  2048
#define TOPK    8
#define NKEY    (K1GRID * TOPK)   // 16384 keys, 128 KB slab
#define SCAP    128    // per-block staging cap (max rows/block = 120)
#define K2BLK   16     // k2 blocks (16 x 1024 threads = NKEY)

__device__ inline float scalar_to_float(const int* p) {
  int v = *p;
  return (v >= 0 && v < (1 << 20)) ? (float)v : __int_as_float(v);
}

struct Box { float x1, y1, x2, y2; };

__device__ inline Box decode_clip(float4 r, float4 p, float W, float H) {
  float w = p.z - p.x, h = p.w - p.y;
  float cx = p.x + 0.5f * w, cy = p.y + 0.5f * h;
  float dx = r.x / 10.f, dy = r.y / 10.f;
  float dw = fminf(r.z / 5.f, XCLIP), dh = fminf(r.w / 5.f, XCLIP);
  float pcx = dx * w + cx, pcy = dy * h + cy;
  float pw = __expf(dw) * w, ph = __expf(dh) * h;
  Box b;
  b.x1 = fminf(fmaxf(pcx - 0.5f * pw, 0.f), W);
  b.y1 = fminf(fmaxf(pcy - 0.5f * ph, 0.f), H);
  b.x2 = fminf(fmaxf(pcx + 0.5f * pw, 0.f), W);
  b.y2 = fminf(fmaxf(pcy + 0.5f * ph, 0.f), H);
  return b;
}

// K1: global_load_lds double-buffer (8 blocks/CU). Valid rows append packed
// keys to LDS staging. Block end: rank-based top-8 extraction (no shuffle
// chains) into a fixed 8-slot slab. Block 0 zeroes the 3 control words.
__global__ __launch_bounds__(256) void k1_score(
    const float* __restrict__ logits, const float* __restrict__ reg,
    const float* __restrict__ prop, const int* __restrict__ ph,
    const int* __restrict__ pw, unsigned long long* __restrict__ buckets,
    unsigned int* __restrict__ ctl, int N) {
  __shared__ float4 tile[2][TILE4];          // 18432 B
  __shared__ unsigned long long candS[SCAP]; // 1024 B
  __shared__ int candN;
  const int t = threadIdx.x, wv = t >> 6, lane = t & 63;
  if (t == 0) candN = 0;
  if (t < SCAP) candS[t] = 0ULL;
  if (blockIdx.x == 0 && t < 3) ctl[t * 16] = 0u;   // counter, done1, done2
  const float W = scalar_to_float(pw), H = scalar_to_float(ph);
  const int nchunks = (N + CHUNK - 1) / CHUNK;

  auto stage = [&](int cc, int b) {
    const int rows = min(CHUNK, N - cc * CHUNK);
    const int nf = rows * 91, nf4 = nf >> 2;
    const float4* s4 = (const float4*)(logits + (size_t)cc * CHUNK * 91);
    float4* dst = &tile[b][0];
    #pragma unroll
    for (int k = 0; k < 3; ++k) {
      int b4 = (wv + (k << 2)) << 6;        // load L = wv+4k, wave-uniform base
      if (b4 < nf4) {
        int g = b4 + lane;
        if (g > nf4 - 1) g = nf4 - 1;       // clamped dups land in pad slots
        __builtin_amdgcn_global_load_lds(
            (const __attribute__((address_space(1))) void*)(s4 + g),
            (__attribute__((address_space(3))) void*)(dst + b4),
            16, 0, 0);
      }
    }
    for (int i = (nf4 << 2) + t; i < nf; i += 256)   // generic-N tail only
      ((float*)dst)[i] = logits[(size_t)cc * CHUNK * 91 + i];
  };

  int c = blockIdx.x;
  int cur = 0;
  if (c < nchunks) stage(c, 0);
  __syncthreads();                          // covers candS/candN init too
  while (c < nchunks) {
    const int cn = c + gridDim.x;
    if (cn < nchunks) stage(cn, cur ^ 1);   // in flight during compute below
    const int rows = min(CHUNK, N - c * CHUNK);
    const int r = t >> 3, s = t & 7;
    if (r < rows) {
      const float* rowp = (const float*)&tile[cur][0] + r * 91;
      float mv = -3.402823466e38f; int mi = 1 << 20;
      float e0 = 0.f, e1 = 0.f;
      #pragma unroll
      for (int k = 0; k < 12; ++k) {
        int j = s + (k << 3);
        if (j < 91) {
          float v = rowp[j];
          float ex = __expf(v);
          if (k & 1) e1 += ex; else e0 += ex;
          if (v > mv) { mv = v; mi = j; }
        }
      }
      float e = e0 + e1;
      #pragma unroll
      for (int m = 1; m <= 4; m <<= 1) {
        float ov = __shfl_xor(mv, m, 64);
        int   oi = __shfl_xor(mi, m, 64);
        float oe = __shfl_xor(e, m, 64);
        e += oe;
        if (ov > mv || (ov == mv && oi < mi)) { mv = ov; mi = oi; }
      }
      if (s == 0) {
        float top1 = __expf(mv) / e;
        const int row = c * CHUNK + r;
        float4 rg = ((const float4*)reg)[row];
        float4 pp = ((const float4*)prop)[row];
        Box b = decode_clip(rg, pp, W, H);
        bool valid = (top1 > 0.05f) && ((b.x2 - b.x1) >= 0.01f) && ((b.y2 - b.y1) >= 0.01f);
        if (valid) {
          unsigned int low = ((0x1FFFFFFu - (unsigned int)row) << 7) |
                             (unsigned int)mi;
          unsigned long long key =
              ((unsigned long long)__float_as_uint(top1) << 32) |
              (unsigned long long)low;
          int pos = atomicAdd(&candN, 1);
          if (pos < SCAP) candS[pos] = key;
        }
      }
    }
    __syncthreads();                        // drains staging vmcnt AFTER compute
    cur ^= 1;
    c = cn;
  }
  __syncthreads();
  // zero my slab slots (unfilled ranks must read back as 0)
  if (t < TOPK) buckets[(size_t)blockIdx.x * TOPK + t] = 0ULL;
  __syncthreads();                          // zero-writes drained before ranks
  // rank-based top-8: keys are unique (row id embedded), ranks are unique
  if (t < SCAP) {
    unsigned long long my = candS[t];
    if (my != 0ULL) {
      int r = 0;
      for (int j = 0; j < SCAP; ++j) r += (candS[j] > my) ? 1 : 0;
      if (r < TOPK) buckets[(size_t)blockIdx.x * TOPK + r] = my;
    }
  }
}

// K2: 16 blocks x 1024. One slab key per thread (register-cached).
// LDS hist -> partials -> done1 spin -> cutoff -> compact to dense cand ->
// done2; block 0 spins then runs rank + suppression-matrix NMS on <=256.
__global__ __launch_bounds__(1024) void k2_tail(
    const unsigned long long* __restrict__ buckets,
    unsigned int* __restrict__ histp, unsigned long long* __restrict__ cand,
    unsigned int* __restrict__ ctl,
    const float* __restrict__ reg, const float* __restrict__ prop,
    const int* __restrict__ ph, const int* __restrict__ pw,
    float* __restrict__ out, int N) {
  __shared__ unsigned int lh[NBINS];
  __shared__ unsigned int wsum[16];
  __shared__ unsigned int wtail[16];
  __shared__ int bstar;
  __shared__ unsigned long long keys[CAPW];
  __shared__ float rx1[CAPW], ry1[CAPW], rx2[CAPW], ry2[CAPW], rsc[CAPW];
  __shared__ int rlab[CAPW];
  __shared__ unsigned int sup[CAPW * 8];
  __shared__ unsigned int rowAny[8];
  __shared__ int keepL[DET];
  __shared__ int nkS;
  unsigned int* counter = ctl;
  unsigned int* done1 = ctl + 16;
  unsigned int* done2 = ctl + 32;
  const int t = threadIdx.x;
  const int lane = t & 63, w = t >> 6;
  // ---- P1: my key -> LDS hist ----
  lh[t] = 0u;
  if (t == 0) { bstar = 0; nkS = 0; }
  __syncthreads();
  const unsigned long long myKey = buckets[(size_t)blockIdx.x * 1024 + t];
  int mybin = -1;
  if (myKey != 0ULL) {
    float s = __uint_as_float((unsigned int)(myKey >> 32));
    mybin = (int)(s * (float)NBINS);
    if (mybin > NBINS - 1) mybin = NBINS - 1;
    atomicAdd(&lh[mybin], 1u);
  }
  __syncthreads();
  histp[blockIdx.x * NBINS + t] = lh[t];
  __syncthreads();
  if (t == 0) {
    __threadfence();
    atomicAdd(done1, 1u);
    while (__hip_atomic_load(done1, __ATOMIC_ACQUIRE, __HIP_MEMORY_SCOPE_AGENT)
           < (unsigned int)K2BLK) { }
  }
  __syncthreads();
  // ---- P2: sum partials + suffix scan + cutoff ----
  unsigned int h0 = 0u;
  #pragma unroll
  for (int b = 0; b < K2BLK; ++b) h0 += histp[b * NBINS + t];
  unsigned int v = h0;
  #pragma unroll
  for (int m = 1; m < 64; m <<= 1) {
    unsigned int o = __shfl_down(v, m, 64);
    if (lane + m < 64) v += o;
  }
  if (lane == 0) wsum[w] = v;
  __syncthreads();
  if (w == 0) {
    unsigned int u = (lane < 16) ? wsum[lane] : 0u;
    unsigned int inc = u;
    #pragma unroll
    for (int m = 1; m < 16; m <<= 1) {
      unsigned int o = __shfl_down(inc, m, 64);
      if (lane + m < 16) inc += o;
    }
    if (lane < 16) wtail[lane] = inc - u;
  }
  __syncthreads();
  const unsigned int St = v + wtail[w];
  const unsigned int St1 = St - h0;
  if (St >= TARGETC && St1 < TARGETC) {
    int b = (St > CAPW) ? t + 1 : t;
    if (b > NBINS - 1) b = NBINS - 1;
    bstar = b;
  }
  __syncthreads();
  const int bs = bstar;
  // ---- P3: compact my register key into dense cand ----
  if (mybin >= bs && myKey != 0ULL) {
    unsigned int pos = atomicAdd(counter, 1u);
    if (pos < CAPW)
      __hip_atomic_store(&cand[pos], myKey, __ATOMIC_RELEASE,
                         __HIP_MEMORY_SCOPE_AGENT);
  }
  __syncthreads();
  if (t == 0) {
    __threadfence();
    atomicAdd(done2, 1u);
  }
  if (blockIdx.x != 0) return;
  // ---- P4: block 0 waits, loads dense keys ----
  if (t == 0) {
    while (__hip_atomic_load(done2, __ATOMIC_ACQUIRE, __HIP_MEMORY_SCOPE_AGENT)
           < (unsigned int)K2BLK) { }
  }
  __syncthreads();
  unsigned int cnt_u = __hip_atomic_load(counter, __ATOMIC_ACQUIRE,
                                         __HIP_MEMORY_SCOPE_AGENT);
  const int count = (cnt_u < (unsigned int)CAPW) ? (int)cnt_u : CAPW;
  if (t < CAPW)
    keys[t] = (t < count)
        ? __hip_atomic_load(&cand[t], __ATOMIC_RELAXED, __HIP_MEMORY_SCOPE_AGENT)
        : 0ULL;
  __syncthreads();
  const float W = scalar_to_float(pw), H = scalar_to_float(ph);
  // ---- P5: rank-order + decode ----
  if (t < count) {
    unsigned long long k = keys[t];
    int r = 0;
    for (int j = 0; j < count; ++j) r += (keys[j] > k) ? 1 : 0;
    unsigned int low = (unsigned int)(k & 0xFFFFFFFFULL);
    int lab = (int)(low & 127u);
    int idx = (int)(0x1FFFFFFu - (low >> 7));
    if (idx < 0) idx = 0;
    if (idx > N - 1) idx = N - 1;
    float4 rr = ((const float4*)reg)[idx];
    float4 pp = ((const float4*)prop)[idx];
    Box b = decode_clip(rr, pp, W, H);
    rx1[r] = b.x1; ry1[r] = b.y1; rx2[r] = b.x2; ry2[r] = b.y2;
    rsc[r] = __uint_as_float((unsigned int)(k >> 32));
    rlab[r] = lab;
  }
  sup[t] = 0u; sup[t + 1024] = 0u;
  if (t < 8) rowAny[t] = 0u;
  __syncthreads();
  // ---- P6: pairwise suppression matrix ----
  for (int p = t; p < (count << 8); p += 1024) {
    int a = p >> 8, b = p & 255;
    if (a < b && b < count && rlab[a] == rlab[b]) {
      float ax = fmaxf(rx1[a], rx1[b]), ay = fmaxf(ry1[a], ry1[b]);
      float bx = fminf(rx2[a], rx2[b]), by = fminf(ry2[a], ry2[b]);
      float iw = fmaxf(bx - ax, 0.f), ih = fmaxf(by - ay, 0.f);
      float inter = iw * ih;
      float a1 = (rx2[a] - rx1[a]) * (ry2[a] - ry1[a]);
      float a2 = (rx2[b] - rx1[b]) * (ry2[b] - ry1[b]);
      if (inter / (a1 + a2 - inter) > 0.5f) {
        atomicOr(&sup[a * 8 + (b >> 5)], 1u << (b & 31));
        atomicOr(&rowAny[a >> 5], 1u << (a & 31));
      }
    }
  }
  __syncthreads();
  // ---- P7: serial greedy resolve (thread 0, masks in named registers) ----
  if (t == 0) {
    unsigned int m0 = 0, m1 = 0, m2 = 0, m3 = 0, m4 = 0, m5 = 0, m6 = 0, m7 = 0;
    int nk = 0;
#define RESOLVE_WORD(WI, MREG)                                          \
    if (nk < DET && (WI) * 32 < count) {                                \
      unsigned int anyw = rowAny[WI];                                   \
      int lim = count - (WI) * 32; if (lim > 32) lim = 32;              \
      for (int b = 0; b < lim; ++b) {                                   \
        if (nk >= DET) break;                                           \
        if (!((MREG >> b) & 1u)) {                                      \
          int p = (WI) * 32 + b;                                        \
          keepL[nk++] = p;                                              \
          if ((anyw >> b) & 1u) {                                       \
            const unsigned int* row = &sup[p * 8];                      \
            m0 |= row[0]; m1 |= row[1]; m2 |= row[2]; m3 |= row[3];     \
            m4 |= row[4]; m5 |= row[5]; m6 |= row[6]; m7 |= row[7];     \
          }                                                             \
        }                                                               \
      }                                                                 \
    }
    RESOLVE_WORD(0, m0)
    RESOLVE_WORD(1, m1)
    RESOLVE_WORD(2, m2)
    RESOLVE_WORD(3, m3)
    RESOLVE_WORD(4, m4)
    RESOLVE_WORD(5, m5)
    RESOLVE_WORD(6, m6)
    RESOLVE_WORD(7, m7)
#undef RESOLVE_WORD
    nkS = nk;
  }
  __syncthreads();
  // ---- P8: output ----
  if (t < DET) {
    int nk = nkS;
    bool vld = t < nk;
    int p = vld ? keepL[t] : 0;
    out[t * 4 + 0] = vld ? rx1[p] : 0.f;
    out[t * 4 + 1] = vld ? ry1[p] : 0.f;
    out[t * 4 + 2] = vld ? rx2[p] : 0.f;
    out[t * 4 + 3] = vld ? ry2[p] : 0.f;
    out[400 + t] = vld ? rsc[p] : 0.f;
    out[500 + t] = vld ? (float)rlab[p] : -1.f;
  }
}

extern "C" void kernel_launch(void* const* d_in, const int* in_sizes, int n_in,
                              void* d_out, int out_size, void* d_ws, size_t ws_size,
                              hipStream_t stream) {
  const float* logits = (const float*)d_in[0];
  const float* reg    = (const float*)d_in[1];
  const float* prop   = (const float*)d_in[2];
  const int*   ph     = (const int*)d_in[3];
  const int*   pw     = (const int*)d_in[4];
  float* out = (float*)d_out;

  const int N = in_sizes[1] / 4;

  char* ws = (char*)d_ws;
  unsigned int* ctl = (unsigned int*)ws;                       // 64 u32
  unsigned long long* buckets = (unsigned long long*)(ws + 256);  // NKEY u64
  unsigned int* histp = (unsigned int*)(ws + 256 + NKEY * 8); // K2BLK*NBINS u32
  unsigned long long* cand =
      (unsigned long long*)(ws + 256 + NKEY * 8 + K2BLK * NBINS * 4); // CAPW u64

  k1_score<<<K1GRID, 256, 0, stream>>>(logits, reg, prop, ph, pw, buckets, ctl, N);
  k2_tail<<<K2BLK, 1024, 0, stream>>>(buckets, histp, cand, ctl,
                                      reg, prop, ph, pw, out, N);
}

// Round 21
// 52.225 us; speedup vs baseline: 1.0655x; 1.0655x over previous
//
#include <hip/hip_runtime.h>

#define NBINS   1024
#define TARGETC 192
#define CAPW    256
#define DET     100
#define XCLIP   4.135166556742356f
#define CHUNK   24
#define TILE4   576    // 546 used float4 slots + clamp pad
#define K1GRID  2048
#define TOPK    8
#define NKEY    (K1GRID * TOPK)   // 16384 keys, 128 KB slab
#define SCAP    128    // per-block staging cap (max rows/block = 120)

__device__ inline float scalar_to_float(const int* p) {
  int v = *p;
  return (v >= 0 && v < (1 << 20)) ? (float)v : __int_as_float(v);
}

struct Box { float x1, y1, x2, y2; };

__device__ inline Box decode_clip(float4 r, float4 p, float W, float H) {
  float w = p.z - p.x, h = p.w - p.y;
  float cx = p.x + 0.5f * w, cy = p.y + 0.5f * h;
  float dx = r.x / 10.f, dy = r.y / 10.f;
  float dw = fminf(r.z / 5.f, XCLIP), dh = fminf(r.w / 5.f, XCLIP);
  float pcx = dx * w + cx, pcy = dy * h + cy;
  float pw = __expf(dw) * w, ph = __expf(dh) * h;
  Box b;
  b.x1 = fminf(fmaxf(pcx - 0.5f * pw, 0.f), W);
  b.y1 = fminf(fmaxf(pcy - 0.5f * ph, 0.f), H);
  b.x2 = fminf(fmaxf(pcx + 0.5f * pw, 0.f), W);
  b.y2 = fminf(fmaxf(pcy + 0.5f * ph, 0.f), H);
  return b;
}

// K1: global_load_lds double-buffer (8 blocks/CU). Valid rows append packed
// keys to LDS staging (LDS atomics only). Block end: rank-based top-8
// extraction with a FIXED-trip unrolled loop (8 ds_reads per waitcnt, no
// serial LDS-latency chain) into a fixed 8-slot slab.
__global__ __launch_bounds__(256) void k1_score(
    const float* __restrict__ logits, const float* __restrict__ reg,
    const float* __restrict__ prop, const int* __restrict__ ph,
    const int* __restrict__ pw, unsigned long long* __restrict__ buckets,
    int N) {
  __shared__ float4 tile[2][TILE4];          // 18432 B
  __shared__ unsigned long long candS[SCAP]; // 1024 B
  __shared__ int candN;
  const int t = threadIdx.x, wv = t >> 6, lane = t & 63;
  if (t == 0) candN = 0;
  if (t < SCAP) candS[t] = 0ULL;
  const float W = scalar_to_float(pw), H = scalar_to_float(ph);
  const int nchunks = (N + CHUNK - 1) / CHUNK;

  auto stage = [&](int cc, int b) {
    const int rows = min(CHUNK, N - cc * CHUNK);
    const int nf = rows * 91, nf4 = nf >> 2;
    const float4* s4 = (const float4*)(logits + (size_t)cc * CHUNK * 91);
    float4* dst = &tile[b][0];
    #pragma unroll
    for (int k = 0; k < 3; ++k) {
      int b4 = (wv + (k << 2)) << 6;        // load L = wv+4k, wave-uniform base
      if (b4 < nf4) {
        int g = b4 + lane;
        if (g > nf4 - 1) g = nf4 - 1;       // clamped dups land in pad slots
        __builtin_amdgcn_global_load_lds(
            (const __attribute__((address_space(1))) void*)(s4 + g),
            (__attribute__((address_space(3))) void*)(dst + b4),
            16, 0, 0);
      }
    }
    for (int i = (nf4 << 2) + t; i < nf; i += 256)   // generic-N tail only
      ((float*)dst)[i] = logits[(size_t)cc * CHUNK * 91 + i];
  };

  int c = blockIdx.x;
  int cur = 0;
  if (c < nchunks) stage(c, 0);
  __syncthreads();                          // covers candS/candN init too
  while (c < nchunks) {
    const int cn = c + gridDim.x;
    if (cn < nchunks) stage(cn, cur ^ 1);   // in flight during compute below
    const int rows = min(CHUNK, N - c * CHUNK);
    const int r = t >> 3, s = t & 7;
    if (r < rows) {
      const float* rowp = (const float*)&tile[cur][0] + r * 91;
      float mv = -3.402823466e38f; int mi = 1 << 20;
      float e0 = 0.f, e1 = 0.f;
      #pragma unroll
      for (int k = 0; k < 12; ++k) {
        int j = s + (k << 3);
        if (j < 91) {
          float v = rowp[j];
          float ex = __expf(v);
          if (k & 1) e1 += ex; else e0 += ex;
          if (v > mv) { mv = v; mi = j; }
        }
      }
      float e = e0 + e1;
      #pragma unroll
      for (int m = 1; m <= 4; m <<= 1) {
        float ov = __shfl_xor(mv, m, 64);
        int   oi = __shfl_xor(mi, m, 64);
        float oe = __shfl_xor(e, m, 64);
        e += oe;
        if (ov > mv || (ov == mv && oi < mi)) { mv = ov; mi = oi; }
      }
      if (s == 0) {
        float top1 = __expf(mv) / e;
        const int row = c * CHUNK + r;
        float4 rg = ((const float4*)reg)[row];
        float4 pp = ((const float4*)prop)[row];
        Box b = decode_clip(rg, pp, W, H);
        bool valid = (top1 > 0.05f) && ((b.x2 - b.x1) >= 0.01f) && ((b.y2 - b.y1) >= 0.01f);
        if (valid) {
          unsigned int low = ((0x1FFFFFFu - (unsigned int)row) << 7) |
                             (unsigned int)mi;
          unsigned long long key =
              ((unsigned long long)__float_as_uint(top1) << 32) |
              (unsigned long long)low;
          int pos = atomicAdd(&candN, 1);
          if (pos < SCAP) candS[pos] = key;
        }
      }
    }
    __syncthreads();                        // drains staging vmcnt AFTER compute
    cur ^= 1;
    c = cn;
  }
  __syncthreads();
  // zero my slab slots (unfilled ranks must read back as 0)
  if (t < TOPK) buckets[(size_t)blockIdx.x * TOPK + t] = 0ULL;
  __syncthreads();                          // zero-stores drained (vmcnt) first
  // rank-based top-8: fixed-trip unrolled loop (keys unique -> unique ranks)
  if (t < SCAP) {
    unsigned long long my = candS[t];
    if (my != 0ULL) {
      int r = 0;
      #pragma unroll 8
      for (int j = 0; j < SCAP; ++j) r += (candS[j] > my) ? 1 : 0;
      if (r < TOPK) buckets[(size_t)blockIdx.x * TOPK + r] = my;
    }
  }
}

// K2: single block, 1024 threads. Slab read ONCE into registers (16 keys
// each, static-unrolled) -> 4-sharded LDS hist -> suffix-scan cutoff ->
// register compaction -> fixed-trip unrolled rank -> fixed-trip unrolled
// suppression matrix -> register-bitmask greedy resolve -> output.
__global__ __launch_bounds__(1024) void k2_tail(
    const unsigned long long* __restrict__ buckets,
    const float* __restrict__ reg, const float* __restrict__ prop,
    const int* __restrict__ ph, const int* __restrict__ pw,
    float* __restrict__ out, int N) {
  __shared__ unsigned int lh[4][NBINS];    // sharded hist, 16 KB
  __shared__ unsigned long long keys[CAPW];
  __shared__ unsigned int wsum[16];
  __shared__ unsigned int wtail[16];
  __shared__ int bstar;
  __shared__ unsigned int gcnt;
  __shared__ float rx1[CAPW], ry1[CAPW], rx2[CAPW], ry2[CAPW], rsc[CAPW];
  __shared__ int rlab[CAPW];
  __shared__ unsigned int sup[CAPW * 8];
  __shared__ unsigned int rowAny[8];
  __shared__ int keepL[DET];
  __shared__ int nkS;
  const int t = threadIdx.x;
  const int lane = t & 63, w = t >> 6;
  for (int i = t; i < 4 * NBINS; i += 1024) ((unsigned int*)lh)[i] = 0u;
  if (t < CAPW) keys[t] = 0ULL;
  if (t == 0) { bstar = 0; gcnt = 0u; nkS = 0; }
  __syncthreads();
  // ---- P1: load my 16 slab keys into registers (one pass, all in flight) ----
  const ulonglong2* B2 = (const ulonglong2*)buckets;
  ulonglong2 v8[8];
  #pragma unroll
  for (int i = 0; i < 8; ++i) v8[i] = B2[t + (i << 10)];
  const int sh = t & 3;
  #pragma unroll
  for (int i = 0; i < 8; ++i) {
    if (v8[i].x) {
      float s = __uint_as_float((unsigned int)(v8[i].x >> 32));
      int b = (int)(s * (float)NBINS);
      if (b > NBINS - 1) b = NBINS - 1;
      atomicAdd(&lh[sh][b], 1u);
    }
    if (v8[i].y) {
      float s = __uint_as_float((unsigned int)(v8[i].y >> 32));
      int b = (int)(s * (float)NBINS);
      if (b > NBINS - 1) b = NBINS - 1;
      atomicAdd(&lh[sh][b], 1u);
    }
  }
  __syncthreads();
  // ---- P2: suffix scan + cutoff ----
  const unsigned int h0 = lh[0][t] + lh[1][t] + lh[2][t] + lh[3][t];
  unsigned int v = h0;
  #pragma unroll
  for (int m = 1; m < 64; m <<= 1) {
    unsigned int o = __shfl_down(v, m, 64);
    if (lane + m < 64) v += o;
  }
  if (lane == 0) wsum[w] = v;
  __syncthreads();
  if (w == 0) {
    unsigned int u = (lane < 16) ? wsum[lane] : 0u;
    unsigned int inc = u;
    #pragma unroll
    for (int m = 1; m < 16; m <<= 1) {
      unsigned int o = __shfl_down(inc, m, 64);
      if (lane + m < 16) inc += o;
    }
    if (lane < 16) wtail[lane] = inc - u;
  }
  __syncthreads();
  const unsigned int St = v + wtail[w];
  const unsigned int St1 = St - h0;
  if (St >= TARGETC && St1 < TARGETC) {
    int b = (St > CAPW) ? t + 1 : t;
    if (b > NBINS - 1) b = NBINS - 1;
    bstar = b;
  }
  __syncthreads();
  const int bs = bstar;
  // ---- P3: compact my register keys (bin >= bs guaranteed <= CAPW total) ----
  #pragma unroll
  for (int i = 0; i < 8; ++i) {
    #pragma unroll
    for (int e = 0; e < 2; ++e) {
      unsigned long long key = e ? v8[i].y : v8[i].x;
      if (key) {
        float s = __uint_as_float((unsigned int)(key >> 32));
        int b = (int)(s * (float)NBINS);
        if (b > NBINS - 1) b = NBINS - 1;
        if (b >= bs) {
          unsigned int pos = atomicAdd(&gcnt, 1u);
          if (pos < CAPW) keys[pos] = key;
        }
      }
    }
  }
  __syncthreads();
  const int count = (gcnt < (unsigned int)CAPW) ? (int)gcnt : CAPW;
  const float W = scalar_to_float(pw), H = scalar_to_float(ph);
  // ---- P4: rank (fixed-trip, unrolled; zero-padded keys never outrank) ----
  if (t < CAPW) {
    unsigned long long my = keys[t];
    int r = 0;
    #pragma unroll 8
    for (int j = 0; j < CAPW; ++j) r += (keys[j] > my) ? 1 : 0;
    if (t < count) {
      unsigned int low = (unsigned int)(my & 0xFFFFFFFFULL);
      int lab = (int)(low & 127u);
      int idx = (int)(0x1FFFFFFu - (low >> 7));
      if (idx < 0) idx = 0;
      if (idx > N - 1) idx = N - 1;
      float4 rr = ((const float4*)reg)[idx];
      float4 pp = ((const float4*)prop)[idx];
      Box b = decode_clip(rr, pp, W, H);
      rx1[r] = b.x1; ry1[r] = b.y1; rx2[r] = b.x2; ry2[r] = b.y2;
      rsc[r] = __uint_as_float((unsigned int)(my >> 32));
      rlab[r] = lab;
    } else {
      rlab[t] = -1 - t;                    // distinct negatives: never match
      rx1[t] = 0.f; ry1[t] = 0.f; rx2[t] = 0.f; ry2[t] = 0.f; rsc[t] = 0.f;
    }
  }
  sup[t] = 0u; sup[t + 1024] = 0u;
  if (t < 8) rowAny[t] = 0u;
  __syncthreads();
  // ---- P5: pairwise suppression matrix (fixed 64 iterations, unrolled) ----
  #pragma unroll 4
  for (int p = t; p < (CAPW << 8); p += 1024) {
    int a = p >> 8, b = p & 255;
    if (a < b && rlab[a] == rlab[b]) {
      float ax = fmaxf(rx1[a], rx1[b]), ay = fmaxf(ry1[a], ry1[b]);
      float bx = fminf(rx2[a], rx2[b]), by = fminf(ry2[a], ry2[b]);
      float iw = fmaxf(bx - ax, 0.f), ih = fmaxf(by - ay, 0.f);
      float inter = iw * ih;
      float a1 = (rx2[a] - rx1[a]) * (ry2[a] - ry1[a]);
      float a2 = (rx2[b] - rx1[b]) * (ry2[b] - ry1[b]);
      if (inter / (a1 + a2 - inter) > 0.5f) {
        atomicOr(&sup[a * 8 + (b >> 5)], 1u << (b & 31));
        atomicOr(&rowAny[a >> 5], 1u << (a & 31));
      }
    }
  }
  __syncthreads();
  // ---- P6: serial greedy resolve (thread 0, masks in named registers) ----
  if (t == 0) {
    unsigned int m0 = 0, m1 = 0, m2 = 0, m3 = 0, m4 = 0, m5 = 0, m6 = 0, m7 = 0;
    int nk = 0;
#define RESOLVE_WORD(WI, MREG)                                          \
    if (nk < DET && (WI) * 32 < count) {                                \
      unsigned int anyw = rowAny[WI];                                   \
      int lim = count - (WI) * 32; if (lim > 32) lim = 32;              \
      for (int b = 0; b < lim; ++b) {                                   \
        if (nk >= DET) break;                                           \
        if (!((MREG >> b) & 1u)) {                                      \
          int p = (WI) * 32 + b;                                        \
          keepL[nk++] = p;                                              \
          if ((anyw >> b) & 1u) {                                       \
            const unsigned int* row = &sup[p * 8];                      \
            m0 |= row[0]; m1 |= row[1]; m2 |= row[2]; m3 |= row[3];     \
            m4 |= row[4]; m5 |= row[5]; m6 |= row[6]; m7 |= row[7];     \
          }                                                             \
        }                                                               \
      }                                                                 \
    }
    RESOLVE_WORD(0, m0)
    RESOLVE_WORD(1, m1)
    RESOLVE_WORD(2, m2)
    RESOLVE_WORD(3, m3)
    RESOLVE_WORD(4, m4)
    RESOLVE_WORD(5, m5)
    RESOLVE_WORD(6, m6)
    RESOLVE_WORD(7, m7)
#undef RESOLVE_WORD
    nkS = nk;
  }
  __syncthreads();
  // ---- P7: output ----
  if (t < DET) {
    int nk = nkS;
    bool vld = t < nk;
    int p = vld ? keepL[t] : 0;
    out[t * 4 + 0] = vld ? rx1[p] : 0.f;
    out[t * 4 + 1] = vld ? ry1[p] : 0.f;
    out[t * 4 + 2] = vld ? rx2[p] : 0.f;
    out[t * 4 + 3] = vld ? ry2[p] : 0.f;
    out[400 + t] = vld ? rsc[p] : 0.f;
    out[500 + t] = vld ? (float)rlab[p] : -1.f;
  }
}

extern "C" void kernel_launch(void* const* d_in, const int* in_sizes, int n_in,
                              void* d_out, int out_size, void* d_ws, size_t ws_size,
                              hipStream_t stream) {
  const float* logits = (const float*)d_in[0];
  const float* reg    = (const float*)d_in[1];
  const float* prop   = (const float*)d_in[2];
  const int*   ph     = (const int*)d_in[3];
  const int*   pw     = (const int*)d_in[4];
  float* out = (float*)d_out;

  const int N = in_sizes[1] / 4;

  unsigned long long* buckets = (unsigned long long*)d_ws;   // NKEY u64 (128 KB)

  k1_score<<<K1GRID, 256, 0, stream>>>(logits, reg, prop, ph, pw, buckets, N);
  k2_tail<<<1, 1024, 0, stream>>>(buckets, reg, prop, ph, pw, out, N);
}